// Round 7
// baseline (107.000 us; speedup 1.0000x reference)
//
#include <hip/hip_runtime.h>
#include <hip/hip_fp16.h>
#include <math.h>

// ConditionalSigKerMMDDiscriminator — x,y,z: (64,33,8) fp32 -> scalar fp32.
//
//   K      = sigker(rbf(x,x))   [symmetric]
//   L_gen  = sigker(lin(y,y))   [symmetric]
//   L_true = sigker(lin(z,z))   [symmetric]
//   L_mix  = sigker(lin(y,z))   [full]
//   Kinv   = (K+I)^-1;  K*Kinv = I - Kinv  =>  W = Kinv - Kinv^2 (symmetric)
//   out    = sum_ij W[i][j]*(Lg+Lt-2Lm)[j][i]
//
// ws floats: [0]=K [4096]=Lg [8192]=Lt [12288]=Lm

#define SLEN 33

__device__ __forceinline__ float rl(float v, int lane) {
    return __int_as_float(__builtin_amdgcn_readlane(__float_as_int(v), lane));
}

// ---------------------------------------------------------------------------
// Kernel A: 2x2-block wavefront PDE, 16 lanes per pair (4 pairs per wave).
// Lane s (=lane&15) owns block-rows 2s (A: grid rows 4s,4s+1) and 2s+1
// (B: grid rows 4s+2,4s+3). 47 anti-diagonal steps, 8 cells/lane/step.
// inc packed half2 {rowA, rowB} -> one ds_read_b32 per step. Neighbor values
// (grid row 4s-1 = lane s-1's block-B bottom row) via 2 shfls.
// grid = 2584: [0,520) rbf(x,x) tri; +520 lin(y,y); +520 lin(z,z);
// [1560,2584) lin(y,z) full (4 pairs per block).
// ---------------------------------------------------------------------------
__global__ __launch_bounds__(64, 3)
void sigker_pde_kernel(const float* __restrict__ x,
                       const float* __restrict__ y,
                       const float* __restrict__ z,
                       float* __restrict__ ws) {
    __shared__ float4 XiS[4][66];        // staged Xi per pair (4224 B)
    __shared__ __half2 inc2[4 * 520];    // [pair][s*32+t] = {inc[2s][t], inc[2s+1][t]}
                                         // pair stride 520 (8-word pad: bank-shifts quarters)

    const int lane = threadIdx.x;
    const int qt = lane >> 4;            // which pair in this wave (0..3)
    const int s  = lane & 15;            // strip index / build column-pair index

    int b = blockIdx.x, g, loc;
    if (b < 520)       { g = 0; loc = b; }
    else if (b < 1040) { g = 1; loc = b - 520; }
    else if (b < 1560) { g = 2; loc = b - 1040; }
    else               { g = 3; loc = b - 1560; }

    int pair = 4 * loc + qt, gi, gj;
    if (g == 3) {
        gi = pair >> 6; gj = pair & 63;
    } else {
        // lower-triangle (incl diagonal) decode, pair in [0,2080)
        float ff = sqrtf(8.0f * (float)pair + 1.0f);
        gi = (int)((ff - 1.0f) * 0.5f);
        while ((gi + 1) * (gi + 2) / 2 <= pair) ++gi;
        while (gi * (gi + 1) / 2 > pair) --gi;
        gj = pair - gi * (gi + 1) / 2;
    }

    const float* Ap = (g == 0) ? x : ((g == 2) ? z : y);
    const float* Bp = (g == 0) ? x : ((g == 1) ? y : z);
    const float4* As = (const float4*)(Ap + gi * (SLEN * 8));
    const float4* Bs = (const float4*)(Bp + gj * (SLEN * 8));

    // Stage Xi for this quarter's pair; Xj rows 2s..2s+2 in registers.
    for (int k = s; k < 66; k += 16) XiS[qt][k] = As[k];
    float4 q0 = Bs[4*s],   q1 = Bs[4*s+1], q2 = Bs[4*s+2],
           q3 = Bs[4*s+3], q4 = Bs[4*s+4], q5 = Bs[4*s+5];
    __syncthreads();

    __half2* incw = inc2 + qt * 520;

    if (g == 0) {
        // RBF: lane s owns gram columns 2s,2s+1,2s+2 (Xj rows in q0..q5),
        // slides down Xi rows; inc row rr = G-double-diff / 4.
        float p0g, p1g, p2g;
        {
            float4 a0 = XiS[qt][0], a1 = XiS[qt][1];
            float u0=a0.x-q0.x,u1=a0.y-q0.y,u2=a0.z-q0.z,u3=a0.w-q0.w;
            float u4=a1.x-q1.x,u5=a1.y-q1.y,u6=a1.z-q1.z,u7=a1.w-q1.w;
            p0g = __expf(-(u0*u0+u1*u1+u2*u2+u3*u3+u4*u4+u5*u5+u6*u6+u7*u7));
            float v0=a0.x-q2.x,v1=a0.y-q2.y,v2=a0.z-q2.z,v3=a0.w-q2.w;
            float v4=a1.x-q3.x,v5=a1.y-q3.y,v6=a1.z-q3.z,v7=a1.w-q3.w;
            p1g = __expf(-(v0*v0+v1*v1+v2*v2+v3*v3+v4*v4+v5*v5+v6*v6+v7*v7));
            float w0=a0.x-q4.x,w1=a0.y-q4.y,w2=a0.z-q4.z,w3=a0.w-q4.w;
            float w4=a1.x-q5.x,w5=a1.y-q5.y,w6=a1.z-q5.z,w7=a1.w-q5.w;
            p2g = __expf(-(w0*w0+w1*w1+w2*w2+w3*w3+w4*w4+w5*w5+w6*w6+w7*w7));
        }
        float t00 = 0.0f, t01 = 0.0f;
        #pragma unroll 2
        for (int r = 1; r <= 32; ++r) {
            float4 a0 = XiS[qt][2*r], a1 = XiS[qt][2*r+1];
            float u0=a0.x-q0.x,u1=a0.y-q0.y,u2=a0.z-q0.z,u3=a0.w-q0.w;
            float u4=a1.x-q1.x,u5=a1.y-q1.y,u6=a1.z-q1.z,u7=a1.w-q1.w;
            float c0g = __expf(-(u0*u0+u1*u1+u2*u2+u3*u3+u4*u4+u5*u5+u6*u6+u7*u7));
            float v0=a0.x-q2.x,v1=a0.y-q2.y,v2=a0.z-q2.z,v3=a0.w-q2.w;
            float v4=a1.x-q3.x,v5=a1.y-q3.y,v6=a1.z-q3.z,v7=a1.w-q3.w;
            float c1g = __expf(-(v0*v0+v1*v1+v2*v2+v3*v3+v4*v4+v5*v5+v6*v6+v7*v7));
            float w0=a0.x-q4.x,w1=a0.y-q4.y,w2=a0.z-q4.z,w3=a0.w-q4.w;
            float w4=a1.x-q5.x,w5=a1.y-q5.y,w6=a1.z-q5.z,w7=a1.w-q5.w;
            float c2g = __expf(-(w0*w0+w1*w1+w2*w2+w3*w3+w4*w4+w5*w5+w6*w6+w7*w7));
            int rr = r - 1;                       // inc row index
            float iA = 0.25f * ((c1g - c0g) - (p1g - p0g));   // inc[rr][2s]
            float iB = 0.25f * ((c2g - c1g) - (p2g - p1g));   // inc[rr][2s+1]
            if ((rr & 1) == 0) { t00 = iA; t01 = iB; }
            else {
                int sp = rr >> 1;
                incw[sp * 32 + 2*s]     = __halves2half2(__float2half(t00), __float2half(iA));
                incw[sp * 32 + 2*s + 1] = __halves2half2(__float2half(t01), __float2half(iB));
            }
            p0g = c0g; p1g = c1g; p2g = c2g;
        }
    } else {
        // Linear: inc[r][t] = dXi[r]·dXj[t]/4 (no gram). Lane s owns cols
        // 2s,2s+1: dXj from registers, dXi slides over staged Xi rows.
        float e0=(q2.x-q0.x)*0.25f, e1=(q2.y-q0.y)*0.25f,
              e2=(q2.z-q0.z)*0.25f, e3=(q2.w-q0.w)*0.25f,
              e4=(q3.x-q1.x)*0.25f, e5=(q3.y-q1.y)*0.25f,
              e6=(q3.z-q1.z)*0.25f, e7=(q3.w-q1.w)*0.25f;
        float f0=(q4.x-q2.x)*0.25f, f1=(q4.y-q2.y)*0.25f,
              f2=(q4.z-q2.z)*0.25f, f3=(q4.w-q2.w)*0.25f,
              f4=(q5.x-q3.x)*0.25f, f5=(q5.y-q3.y)*0.25f,
              f6=(q5.z-q3.z)*0.25f, f7=(q5.w-q3.w)*0.25f;
        float4 a0 = XiS[qt][0], a1 = XiS[qt][1];
        #pragma unroll 2
        for (int sp = 0; sp < 16; ++sp) {
            float4 a2 = XiS[qt][4*sp+2], a3 = XiS[qt][4*sp+3];
            float4 a4 = XiS[qt][4*sp+4], a5 = XiS[qt][4*sp+5];
            float d0=a2.x-a0.x, d1=a2.y-a0.y, d2=a2.z-a0.z, d3=a2.w-a0.w;
            float d4=a3.x-a1.x, d5=a3.y-a1.y, d6=a3.z-a1.z, d7=a3.w-a1.w;
            float g0v=a4.x-a2.x, g1v=a4.y-a2.y, g2v=a4.z-a2.z, g3v=a4.w-a2.w;
            float g4v=a5.x-a3.x, g5v=a5.y-a3.y, g6v=a5.z-a3.z, g7v=a5.w-a3.w;
            float i00 = d0*e0+d1*e1+d2*e2+d3*e3+d4*e4+d5*e5+d6*e6+d7*e7;
            float i01 = d0*f0+d1*f1+d2*f2+d3*f3+d4*f4+d5*f5+d6*f6+d7*f7;
            float i10 = g0v*e0+g1v*e1+g2v*e2+g3v*e3+g4v*e4+g5v*e5+g6v*e6+g7v*e7;
            float i11 = g0v*f0+g1v*f1+g2v*f2+g3v*f3+g4v*f4+g5v*f5+g6v*f6+g7v*f7;
            incw[sp * 32 + 2*s]     = __halves2half2(__float2half(i00), __float2half(i10));
            incw[sp * 32 + 2*s + 1] = __halves2half2(__float2half(i01), __float2half(i11));
            a0 = a4; a1 = a5;
        }
    }
    __syncthreads();

    // Anti-diagonal wavefront: lane s at step m handles block-col t=m-s for
    // both its blocks A (rows 4s,4s+1) and B (rows 4s+2,4s+3).
    // Boundary: at t==0 all left/diag inputs are 1.0 (kills pre-entry
    // garbage); neighbor (n) values always valid one step behind.
    float cA01 = 1.0f, cA11 = 1.0f, dA = 1.0f;
    float cB01 = 1.0f, cB10 = 1.0f, cB11 = 1.0f;
    const bool stop = (s == 0);
    const __half2* incr = incw + s * 32;
    #pragma unroll 2
    for (int m = 0; m < 47; ++m) {
        float nb0 = __shfl_up(cB10, 1);      // (4s-1, 2t)   from lane s-1
        float nb1 = __shfl_up(cB11, 1);      // (4s-1, 2t+1)
        int t = m - s;
        __half2 hv = incr[t & 31];
        float incA = __low2float(hv), incB = __high2float(hv);
        float nA0 = stop ? 1.0f : nb0;
        float nA1 = stop ? 1.0f : nb1;
        bool t0 = (t == 0);
        float wA0 = t0 ? 1.0f : cA01;
        float wA1 = t0 ? 1.0f : cA11;
        float dAx = t0 ? 1.0f : dA;
        float wB0 = t0 ? 1.0f : cB01;
        float wB1 = t0 ? 1.0f : cB11;
        float dBx = t0 ? 1.0f : cA11;        // pre-update A bottom-right @ t-1
        float iA = incA * incA * (1.0f / 12.0f);
        float C1A = 1.0f + 0.5f * incA + iA;
        float C2A = 1.0f - iA;
        float iB = incB * incB * (1.0f / 12.0f);
        float C1B = 1.0f + 0.5f * incB + iB;
        float C2B = 1.0f - iB;
        float vA00 = (wA0 + nA0 ) * C1A - dAx * C2A;
        float vA01 = (vA00 + nA1 ) * C1A - nA0 * C2A;
        float vA10 = (vA00 + wA1 ) * C1A - wA0 * C2A;
        float vA11 = (vA10 + vA01) * C1A - vA00 * C2A;
        float vB00 = (wB0 + vA10) * C1B - dBx * C2B;
        float vB01 = (vB00 + vA11) * C1B - vA10 * C2B;
        float vB10 = (vB00 + wB1 ) * C1B - wB0 * C2B;
        float vB11 = (vB10 + vB01) * C1B - vB00 * C2B;
        cA01 = vA01; cA11 = vA11; dA = nA1;
        cB01 = vB01; cB10 = vB10; cB11 = vB11;
    }

    if (s == 15) {   // holds grid cell (63,63) = block B bottom-right @ t=31
        float* dst = ws + g * 4096;
        dst[gi * 64 + gj] = cB11;
        if (g != 3) dst[gj * 64 + gi] = cB11;
    }
}

// ---------------------------------------------------------------------------
// Kernel B (fused): 2x2-block Gauss-Jordan inverse of (K+I) + trace.
// 1024 threads (16 waves). Thread (w=tid>>6, c=tid&63) owns rows w*4+i in
// m[4] (static indices, no scratch — proven r4-r6). ROLLED 32-round loop
// (dynamic-uniform readlane, 2-case pivot select) to keep code ~1.5 KB and
// off the I$ cliff. One barrier per round via ping-pong prow.
// ---------------------------------------------------------------------------
__global__ __launch_bounds__(1024, 1)
void gj_trace_kernel(const float* __restrict__ ws, float* __restrict__ out) {
    __shared__ float prow[2][2][64];
    __shared__ float Kls[64 * 65];
    __shared__ float red[16];

    const int tid = threadIdx.x;
    const int c = tid & 63, w = tid >> 6;   // rows w*4+i
    const float* K  = ws;
    const float* Lg = ws + 4096;
    const float* Lt = ws + 8192;
    const float* Lm = ws + 12288;

    float m[4];
    #pragma unroll
    for (int i = 0; i < 4; ++i) {
        int r = w * 4 + i;
        m[i] = K[r * 64 + c] + ((r == c) ? 1.0f : 0.0f);   // K + I
    }

    #pragma unroll 1
    for (int rnd = 0; rnd < 32; ++rnd) {
        const int p0 = 2 * rnd, p1 = p0 + 1;
        const int wp = rnd >> 1;             // wave owning rows p0,p1
        const bool hi = (rnd & 1);           // pivot rows in m[2],m[3] vs m[0],m[1]
        const int buf = rnd & 1;
        if (w == wp) {
            float x0 = hi ? m[2] : m[0];
            float x1 = hi ? m[3] : m[1];
            // 2x2 pivot block inverse (SPD principal block => det > 0)
            float a  = rl(x0, p0), bq = rl(x0, p1);
            float cq = rl(x1, p0), dq = rl(x1, p1);
            float dinv = 1.0f / (a * dq - bq * cq);
            float P00 =  dq * dinv, P01 = -bq * dinv;
            float P10 = -cq * dinv, P11 =  a  * dinv;
            float sp0 = P00 * x0 + P01 * x1;
            float sp1 = P10 * x0 + P11 * x1;
            sp0 = (c == p0) ? P00 : ((c == p1) ? P01 : sp0);
            sp1 = (c == p0) ? P10 : ((c == p1) ? P11 : sp1);
            if (hi) { m[2] = sp0; m[3] = sp1; } else { m[0] = sp0; m[1] = sp1; }
            prow[buf][0][c] = sp0;
            prow[buf][1][c] = sp1;
        }
        __syncthreads();
        float s0 = prow[buf][0][c],  s1 = prow[buf][1][c];
        float q00 = prow[buf][0][p0], q01 = prow[buf][0][p1];
        float q10 = prow[buf][1][p0], q11 = prow[buf][1][p1];
        const int i0 = hi ? 2 : 0;
        #pragma unroll
        for (int i = 0; i < 4; ++i) {
            bool pivotRow = (w == wp) && (i == i0 || i == i0 + 1);
            float f0 = rl(m[i], p0);
            float f1 = rl(m[i], p1);
            float nv = m[i] - f0 * s0 - f1 * s1;
            float wb0 = -(f0 * q00 + f1 * q10);
            float wb1 = -(f0 * q01 + f1 * q11);
            nv = (c == p0) ? wb0 : ((c == p1) ? wb1 : nv);
            if (!pivotRow) m[i] = nv;
        }
        // next round writes prow[buf^1]; its barrier separates buf reuse
    }
    // m[i] = Kinv[w*4+i][c]

    #pragma unroll
    for (int i = 0; i < 4; ++i)
        Kls[(w * 4 + i) * 65 + c] = m[i];
    __syncthreads();

    // acc[i] = (Kinv^2)[w*4+i][c]; row scalar via dynamic-uniform readlane
    float acc[4] = {0.0f, 0.0f, 0.0f, 0.0f};
    #pragma unroll 4
    for (int k = 0; k < 64; ++k) {
        float rv = Kls[k * 65 + c];          // Kinv[k][c]
        #pragma unroll
        for (int i = 0; i < 4; ++i)
            acc[i] = fmaf(rl(m[i], k), rv, acc[i]);
    }

    // W = Kinv - Kinv^2 symmetric => tr(W L) = sum W[r][c]*Lc[r][c]
    float local = 0.0f;
    #pragma unroll
    for (int i = 0; i < 4; ++i) {
        int r = w * 4 + i;
        float lc = Lg[r * 64 + c] + Lt[r * 64 + c] - 2.0f * Lm[r * 64 + c];
        local += (m[i] - acc[i]) * lc;
    }
    #pragma unroll
    for (int off = 32; off > 0; off >>= 1)
        local += __shfl_down(local, off);
    if (c == 0) red[w] = local;
    __syncthreads();
    if (tid == 0) {
        float v = 0.0f;
        #pragma unroll
        for (int i = 0; i < 16; ++i) v += red[i];
        out[0] = v;
    }
}

extern "C" void kernel_launch(void* const* d_in, const int* in_sizes, int n_in,
                              void* d_out, int out_size, void* d_ws, size_t ws_size,
                              hipStream_t stream) {
    const float* x = (const float*)d_in[0];
    const float* y = (const float*)d_in[1];
    const float* z = (const float*)d_in[2];
    float* out = (float*)d_out;
    float* ws  = (float*)d_ws;      // 16384 floats = 64 KB used

    sigker_pde_kernel<<<2584, 64, 0, stream>>>(x, y, z, ws);
    gj_trace_kernel<<<1, 1024, 0, stream>>>(ws, out);
}